// Round 1
// baseline (2319.092 us; speedup 1.0000x reference)
//
#include <hip/hip_runtime.h>
#include <math.h>

#define D_MODEL 256
#define NHEAD 8
#define HDIM 32
#define NLVL 4
#define NPTS 4
#define DFF 1024
#define NLAYERS 6
#define LEN 3060
#define BS 2
#define MROWS (BS * LEN)   // 6120

// ---------------------------------------------------------------------------
// Flatten: src (b, D, H, W) levels -> out (b, t, d); pos likewise + level_embed
// ---------------------------------------------------------------------------
__global__ __launch_bounds__(256) void flatten_kernel(
    const float* __restrict__ s0, const float* __restrict__ s1,
    const float* __restrict__ s2, const float* __restrict__ s3,
    const float* __restrict__ p0, const float* __restrict__ p1,
    const float* __restrict__ p2, const float* __restrict__ p3,
    const float* __restrict__ lemb,
    float* __restrict__ out, float* __restrict__ pos)
{
    int gid = blockIdx.x * 256 + threadIdx.x;
    if (gid >= MROWS * D_MODEL) return;
    int d  = gid & (D_MODEL - 1);
    int bt = gid >> 8;
    int b  = (bt >= LEN) ? 1 : 0;
    int t  = bt - b * LEN;

    int lv, li, hw;
    const float* sp; const float* pp;
    if (t < 2304)      { lv = 0; li = t;        hw = 2304; sp = s0; pp = p0; }
    else if (t < 2880) { lv = 1; li = t - 2304; hw = 576;  sp = s1; pp = p1; }
    else if (t < 3024) { lv = 2; li = t - 2880; hw = 144;  sp = s2; pp = p2; }
    else               { lv = 3; li = t - 3024; hw = 36;   sp = s3; pp = p3; }

    size_t si = (size_t)(b * D_MODEL + d) * hw + li;
    out[gid] = sp[si];
    pos[gid] = pp[si] + lemb[lv * D_MODEL + d];
}

// ---------------------------------------------------------------------------
// Elementwise add (float4): q = out + pos
// ---------------------------------------------------------------------------
__global__ __launch_bounds__(256) void add_kernel(
    const float4* __restrict__ a, const float4* __restrict__ b,
    float4* __restrict__ c, int n4)
{
    int i = blockIdx.x * 256 + threadIdx.x;
    if (i >= n4) return;
    float4 x = a[i], y = b[i];
    c[i] = make_float4(x.x + y.x, x.y + y.y, x.z + y.z, x.w + y.w);
}

// ---------------------------------------------------------------------------
// Tiled fp32 GEMM: C(M,N) = A(M,K) @ W(K,N) + bias, optional ReLU.
// BM=BN=64, BK=16, 256 threads, 4x4 per thread. N % 64 == 0, K % 16 == 0.
// ---------------------------------------------------------------------------
template <bool RELU>
__global__ __launch_bounds__(256) void gemm_kernel(
    const float* __restrict__ A, const float* __restrict__ W,
    const float* __restrict__ bias, float* __restrict__ C,
    int M, int N, int K)
{
    __shared__ float As[16][65];
    __shared__ float Bsh[16][65];

    const int bm = blockIdx.y, bn = blockIdx.x;
    const int row0 = bm * 64, col0 = bn * 64;
    const int tid = threadIdx.x;
    const int tx = tid & 15;        // 0..15  (N dir)
    const int ty = tid >> 4;        // 0..15  (M dir)

    float acc[4][4] = {};

    for (int k0 = 0; k0 < K; k0 += 16) {
        // A tile 64x16 -> As[k][m]
        #pragma unroll
        for (int i = 0; i < 4; ++i) {
            int idx = tid + i * 256;
            int m = idx >> 4, kk = idx & 15;
            int gr = row0 + m;
            As[kk][m] = (gr < M) ? A[(size_t)gr * K + k0 + kk] : 0.f;
        }
        // B tile 16x64 -> Bsh[k][n]
        #pragma unroll
        for (int i = 0; i < 4; ++i) {
            int idx = tid + i * 256;
            int kk = idx >> 6, n = idx & 63;
            Bsh[kk][n] = W[(size_t)(k0 + kk) * N + col0 + n];
        }
        __syncthreads();
        #pragma unroll
        for (int kk = 0; kk < 16; ++kk) {
            float a[4], bvals[4];
            #pragma unroll
            for (int i = 0; i < 4; ++i) a[i] = As[kk][ty * 4 + i];
            #pragma unroll
            for (int j = 0; j < 4; ++j) bvals[j] = Bsh[kk][tx * 4 + j];
            #pragma unroll
            for (int i = 0; i < 4; ++i)
                #pragma unroll
                for (int j = 0; j < 4; ++j)
                    acc[i][j] += a[i] * bvals[j];
        }
        __syncthreads();
    }

    #pragma unroll
    for (int i = 0; i < 4; ++i) {
        int r = row0 + ty * 4 + i;
        if (r >= M) continue;
        #pragma unroll
        for (int j = 0; j < 4; ++j) {
            int cidx = col0 + tx * 4 + j;
            float v = acc[i][j] + bias[cidx];
            if (RELU) v = fmaxf(v, 0.f);
            C[(size_t)r * N + cidx] = v;
        }
    }
}

// ---------------------------------------------------------------------------
// MSDA sampling: softmax over 16 logits + bilinear sample + weighted sum.
// One thread handles (b, t, head, quarter-of-HD): 4 output floats.
// ---------------------------------------------------------------------------
__global__ __launch_bounds__(256) void msda_kernel(
    const float* __restrict__ value,   // (b, t, NH, HD)
    const float* __restrict__ offb,    // (b, t, NH*NL*NP*2)
    const float* __restrict__ attnb,   // (b, t, NH*NL*NP)
    float* __restrict__ outb)          // (b, t, NH*HD)
{
    int gid = blockIdx.x * 256 + threadIdx.x;
    if (gid >= MROWS * NHEAD * 8) return;
    int part = gid & 7;
    int h    = (gid >> 3) & 7;
    int bt   = gid >> 6;
    int b    = (bt >= LEN) ? 1 : 0;
    int t    = bt - b * LEN;

    // softmax over the 16 attention logits of this head
    const float* lg = attnb + (size_t)bt * 128 + h * 16;
    float w[16];
    float mx = -1e30f;
    #pragma unroll
    for (int j = 0; j < 16; ++j) { w[j] = lg[j]; mx = fmaxf(mx, w[j]); }
    float s = 0.f;
    #pragma unroll
    for (int j = 0; j < 16; ++j) { w[j] = __expf(w[j] - mx); s += w[j]; }
    float inv = 1.f / s;

    // reference point of token t
    int li, Wr;
    if (t < 2304)      { li = t;        Wr = 48; }
    else if (t < 2880) { li = t - 2304; Wr = 24; }
    else if (t < 3024) { li = t - 2880; Wr = 12; }
    else               { li = t - 3024; Wr = 6;  }
    float refx = ((li % Wr) + 0.5f) / (float)Wr;
    float refy = ((li / Wr) + 0.5f) / (float)Wr;   // square levels: H == W

    const float* offp    = offb + (size_t)bt * 256 + h * 32;   // (NL, NP, 2)
    const float* valbase = value + (size_t)b * LEN * D_MODEL + h * HDIM + part * 4;

    const int starts[4] = {0, 2304, 2880, 3024};
    const int Ws[4]     = {48, 24, 12, 6};

    float4 acc = make_float4(0.f, 0.f, 0.f, 0.f);

    #pragma unroll
    for (int lv = 0; lv < NLVL; ++lv) {
        int Wl = Ws[lv];
        int st = starts[lv];
        float fW = (float)Wl;
        #pragma unroll
        for (int p = 0; p < NPTS; ++p) {
            float ox = offp[(lv * NPTS + p) * 2 + 0];
            float oy = offp[(lv * NPTS + p) * 2 + 1];
            float x = (refx + ox / fW) * fW - 0.5f;
            float y = (refy + oy / fW) * fW - 0.5f;
            float x0f = floorf(x), y0f = floorf(y);
            float lx = x - x0f, ly = y - y0f;
            int x0 = (int)x0f, y0 = (int)y0f;
            float aw = w[lv * NPTS + p] * inv;
            float tw[4] = {(1.f - lx) * (1.f - ly), lx * (1.f - ly),
                           (1.f - lx) * ly,         lx * ly};
            const int dxs[4] = {0, 1, 0, 1};
            const int dys[4] = {0, 0, 1, 1};
            #pragma unroll
            for (int tap = 0; tap < 4; ++tap) {
                int xi = x0 + dxs[tap], yi = y0 + dys[tap];
                bool valid = (xi >= 0) & (xi < Wl) & (yi >= 0) & (yi < Wl);
                int xc = xi < 0 ? 0 : (xi > Wl - 1 ? Wl - 1 : xi);
                int yc = yi < 0 ? 0 : (yi > Wl - 1 ? Wl - 1 : yi);
                int tt = st + yc * Wl + xc;
                const float4 v = *(const float4*)(valbase + (size_t)tt * D_MODEL);
                float wt = valid ? aw * tw[tap] : 0.f;
                acc.x += wt * v.x; acc.y += wt * v.y;
                acc.z += wt * v.z; acc.w += wt * v.w;
            }
        }
    }
    *(float4*)(outb + (size_t)bt * D_MODEL + h * HDIM + part * 4) = acc;
}

// ---------------------------------------------------------------------------
// Fused residual add + LayerNorm, in-place on `out`. One 64-lane wave per row.
// ---------------------------------------------------------------------------
__global__ __launch_bounds__(256) void add_ln_kernel(
    float* __restrict__ out, const float* __restrict__ add,
    const float* __restrict__ g, const float* __restrict__ be)
{
    int row  = blockIdx.x * 4 + (threadIdx.x >> 6);
    int lane = threadIdx.x & 63;
    if (row >= MROWS) return;

    float4 x = ((const float4*)(out + (size_t)row * D_MODEL))[lane];
    float4 y = ((const float4*)(add + (size_t)row * D_MODEL))[lane];
    x.x += y.x; x.y += y.y; x.z += y.z; x.w += y.w;

    float s  = x.x + x.y + x.z + x.w;
    float ss = x.x * x.x + x.y * x.y + x.z * x.z + x.w * x.w;
    #pragma unroll
    for (int m = 1; m < 64; m <<= 1) {
        s  += __shfl_xor(s, m);
        ss += __shfl_xor(ss, m);
    }
    float mean = s * (1.f / 256.f);
    float var  = ss * (1.f / 256.f) - mean * mean;
    float rstd = rsqrtf(var + 1e-5f);

    float4 gv = ((const float4*)g)[lane];
    float4 bv = ((const float4*)be)[lane];
    float4 o;
    o.x = (x.x - mean) * rstd * gv.x + bv.x;
    o.y = (x.y - mean) * rstd * gv.y + bv.y;
    o.z = (x.z - mean) * rstd * gv.z + bv.z;
    o.w = (x.w - mean) * rstd * gv.w + bv.w;
    ((float4*)(out + (size_t)row * D_MODEL))[lane] = o;
}

// ---------------------------------------------------------------------------
// Tail: spatial_shapes + level_start_index as float32 values
// ---------------------------------------------------------------------------
__global__ void tail_kernel(float* __restrict__ tail)
{
    if (threadIdx.x == 0 && blockIdx.x == 0) {
        const float vals[12] = {48.f, 48.f, 24.f, 24.f, 12.f, 12.f, 6.f, 6.f,
                                0.f, 2304.f, 2880.f, 3024.f};
        #pragma unroll
        for (int i = 0; i < 12; ++i) tail[i] = vals[i];
    }
}

// ---------------------------------------------------------------------------
extern "C" void kernel_launch(void* const* d_in, const int* in_sizes, int n_in,
                              void* d_out, int out_size, void* d_ws, size_t ws_size,
                              hipStream_t stream)
{
    // Input order: setup_inputs() dict order (interleaved src0,pos0,src1,pos1,...).
    // Detect defensively via sizes.
    const float* SRC[4]; const float* POS[4];
    bool interleaved = (in_sizes[1] == in_sizes[0]);
    if (interleaved) {
        SRC[0] = (const float*)d_in[0]; POS[0] = (const float*)d_in[1];
        SRC[1] = (const float*)d_in[2]; POS[1] = (const float*)d_in[3];
        SRC[2] = (const float*)d_in[4]; POS[2] = (const float*)d_in[5];
        SRC[3] = (const float*)d_in[6]; POS[3] = (const float*)d_in[7];
    } else {
        for (int i = 0; i < 4; ++i) {
            SRC[i] = (const float*)d_in[i];
            POS[i] = (const float*)d_in[4 + i];
        }
    }
    const float* lemb  = (const float*)d_in[8];
    const float* Wv    = (const float*)d_in[9];
    const float* bv    = (const float*)d_in[10];
    const float* Woff  = (const float*)d_in[11];
    const float* boff  = (const float*)d_in[12];
    const float* Wa    = (const float*)d_in[13];
    const float* ba    = (const float*)d_in[14];
    const float* Wo    = (const float*)d_in[15];
    const float* bo    = (const float*)d_in[16];
    const float* g1    = (const float*)d_in[17];
    const float* beta1 = (const float*)d_in[18];
    const float* W1    = (const float*)d_in[19];
    const float* bf1   = (const float*)d_in[20];
    const float* W2    = (const float*)d_in[21];
    const float* bf2   = (const float*)d_in[22];
    const float* g2    = (const float*)d_in[23];
    const float* beta2 = (const float*)d_in[24];

    float* out = (float*)d_out;                  // (b, t, D) residual stream
    float* ws  = (float*)d_ws;

    const size_t ACT = (size_t)MROWS * D_MODEL;  // 1,566,720
    float* pos  = ws;
    float* q    = ws + ACT;
    float* val  = ws + 2 * ACT;
    float* off  = ws + 3 * ACT;
    float* attn = ws + 4 * ACT;                  // uses MROWS*128
    float* msda = ws + 4 * ACT + (size_t)MROWS * 128;
    float* tmp  = msda + ACT;
    float* hbuf = tmp + ACT;                     // (MROWS, DFF)

    const int nElem = MROWS * D_MODEL;
    flatten_kernel<<<(nElem + 255) / 256, 256, 0, stream>>>(
        SRC[0], SRC[1], SRC[2], SRC[3], POS[0], POS[1], POS[2], POS[3],
        lemb, out, pos);

    const int n4 = nElem / 4;
    const dim3 gemm_grid_256(256 / 64, (MROWS + 63) / 64);
    const dim3 gemm_grid_128(128 / 64, (MROWS + 63) / 64);
    const dim3 gemm_grid_1024(1024 / 64, (MROWS + 63) / 64);

    for (int l = 0; l < NLAYERS; ++l) {
        const float* Wv_l   = Wv   + (size_t)l * D_MODEL * D_MODEL;
        const float* bv_l   = bv   + l * D_MODEL;
        const float* Woff_l = Woff + (size_t)l * D_MODEL * 256;
        const float* boff_l = boff + l * 256;
        const float* Wa_l   = Wa   + (size_t)l * D_MODEL * 128;
        const float* ba_l   = ba   + l * 128;
        const float* Wo_l   = Wo   + (size_t)l * D_MODEL * D_MODEL;
        const float* bo_l   = bo   + l * D_MODEL;
        const float* W1_l   = W1   + (size_t)l * D_MODEL * DFF;
        const float* bf1_l  = bf1  + l * DFF;
        const float* W2_l   = W2   + (size_t)l * DFF * D_MODEL;
        const float* bf2_l  = bf2  + l * D_MODEL;

        // q = out + pos
        add_kernel<<<(n4 + 255) / 256, 256, 0, stream>>>(
            (const float4*)out, (const float4*)pos, (float4*)q, n4);

        // value = out @ Wv + bv
        gemm_kernel<false><<<gemm_grid_256, 256, 0, stream>>>(
            out, Wv_l, bv_l, val, MROWS, 256, 256);
        // off = q @ Woff + boff
        gemm_kernel<false><<<gemm_grid_256, 256, 0, stream>>>(
            q, Woff_l, boff_l, off, MROWS, 256, 256);
        // attn logits = q @ Wa + ba
        gemm_kernel<false><<<gemm_grid_128, 256, 0, stream>>>(
            q, Wa_l, ba_l, attn, MROWS, 128, 256);

        // deformable sampling
        msda_kernel<<<(MROWS * NHEAD * 8 + 255) / 256, 256, 0, stream>>>(
            val, off, attn, msda);

        // out-proj: tmp = msda @ Wo + bo
        gemm_kernel<false><<<gemm_grid_256, 256, 0, stream>>>(
            msda, Wo_l, bo_l, tmp, MROWS, 256, 256);
        // out = LN(out + tmp)
        add_ln_kernel<<<MROWS / 4, 256, 0, stream>>>(out, tmp, g1 + l * D_MODEL,
                                                     beta1 + l * D_MODEL);

        // h = relu(out @ W1 + bf1)
        gemm_kernel<true><<<gemm_grid_1024, 256, 0, stream>>>(
            out, W1_l, bf1_l, hbuf, MROWS, DFF, 256);
        // tmp = h @ W2 + bf2
        gemm_kernel<false><<<gemm_grid_256, 256, 0, stream>>>(
            hbuf, W2_l, bf2_l, tmp, MROWS, 256, DFF);
        // out = LN(out + tmp)
        add_ln_kernel<<<MROWS / 4, 256, 0, stream>>>(out, tmp, g2 + l * D_MODEL,
                                                     beta2 + l * D_MODEL);
    }

    tail_kernel<<<1, 64, 0, stream>>>(out + ACT);
}

// Round 2
// 743.970 us; speedup vs baseline: 3.1172x; 3.1172x over previous
//
#include <hip/hip_runtime.h>
#include <math.h>

#define D_MODEL 256
#define NHEAD 8
#define HDIM 32
#define NLVL 4
#define NPTS 4
#define DFF 1024
#define NLAYERS 6
#define LEN 3060
#define BS 2
#define MROWS (BS * LEN)   // 6120
#define MPAD 6144          // padded rows for GEMM A operands

typedef __attribute__((ext_vector_type(8))) short bf16x8;
typedef __attribute__((ext_vector_type(4))) float f32x4;

__device__ __forceinline__ unsigned short f2bf(float f) {
    union { float f; unsigned u; } v; v.f = f;
    unsigned r = v.u + 0x7FFF + ((v.u >> 16) & 1);
    return (unsigned short)(r >> 16);
}

#define GLDS(gp, lp) __builtin_amdgcn_global_load_lds(                        \
    (const __attribute__((address_space(1))) void*)(gp),                      \
    (__attribute__((address_space(3))) void*)(lp), 16, 0, 0)

// ---------------------------------------------------------------------------
// Flatten: src (b, D, H, W) levels -> out fp32 + out bf16; pos + level_embed
// ---------------------------------------------------------------------------
__global__ __launch_bounds__(256) void flatten_kernel(
    const float* __restrict__ s0, const float* __restrict__ s1,
    const float* __restrict__ s2, const float* __restrict__ s3,
    const float* __restrict__ p0, const float* __restrict__ p1,
    const float* __restrict__ p2, const float* __restrict__ p3,
    const float* __restrict__ lemb,
    float* __restrict__ out, unsigned short* __restrict__ outbf,
    float* __restrict__ pos)
{
    int gid = blockIdx.x * 256 + threadIdx.x;
    if (gid >= MROWS * D_MODEL) return;
    int d  = gid & (D_MODEL - 1);
    int bt = gid >> 8;
    int b  = (bt >= LEN) ? 1 : 0;
    int t  = bt - b * LEN;

    int lv, li, hw;
    const float* sp; const float* pp;
    if (t < 2304)      { lv = 0; li = t;        hw = 2304; sp = s0; pp = p0; }
    else if (t < 2880) { lv = 1; li = t - 2304; hw = 576;  sp = s1; pp = p1; }
    else if (t < 3024) { lv = 2; li = t - 2880; hw = 144;  sp = s2; pp = p2; }
    else               { lv = 3; li = t - 3024; hw = 36;   sp = s3; pp = p3; }

    size_t si = (size_t)(b * D_MODEL + d) * hw + li;
    float v = sp[si];
    out[gid]   = v;
    outbf[gid] = f2bf(v);
    pos[gid]   = pp[si] + lemb[lv * D_MODEL + d];
}

// ---------------------------------------------------------------------------
// q = out + pos  ->  bf16
// ---------------------------------------------------------------------------
__global__ __launch_bounds__(256) void addq_kernel(
    const float4* __restrict__ a, const float4* __restrict__ b,
    ushort4* __restrict__ qbf, int n4)
{
    int i = blockIdx.x * 256 + threadIdx.x;
    if (i >= n4) return;
    float4 x = a[i], y = b[i];
    qbf[i] = make_ushort4(f2bf(x.x + y.x), f2bf(x.y + y.y),
                          f2bf(x.z + y.z), f2bf(x.w + y.w));
}

// ---------------------------------------------------------------------------
// Weight transpose + bf16 convert:  W[K][N] fp32 -> Wt[N][K] bf16.
// One launch for all layers/weights; 32x32 tiles via LDS.
// ---------------------------------------------------------------------------
__global__ __launch_bounds__(256) void wconv_kernel(
    const float* __restrict__ Wv, const float* __restrict__ Woff,
    const float* __restrict__ Wa, const float* __restrict__ Wo,
    const float* __restrict__ W1, const float* __restrict__ W2,
    unsigned short* __restrict__ Wv_t, unsigned short* __restrict__ Woffa_t,
    unsigned short* __restrict__ Wo_t, unsigned short* __restrict__ W1_t,
    unsigned short* __restrict__ W2_t)
{
    __shared__ float tile[32][33];
    int bid = blockIdx.x;
    int layer = bid / 736, r = bid % 736;
    const float* src; unsigned short* dst;
    int N, tk, tn, dstRowOff = 0, dstLd;
    if (r < 64)       { src = Wv  + layer*65536;  dst = Wv_t   + layer*65536;  N = 256;  int t2 = r;       tk = t2 >> 3; tn = t2 & 7;  dstLd = 256;  }
    else if (r < 128) { src = Woff+ layer*65536;  dst = Woffa_t+ layer*98304;  N = 256;  int t2 = r - 64;  tk = t2 >> 3; tn = t2 & 7;  dstLd = 256;  }
    else if (r < 160) { src = Wa  + layer*32768;  dst = Woffa_t+ layer*98304;  N = 128;  int t2 = r - 128; tk = t2 >> 2; tn = t2 & 3;  dstLd = 256;  dstRowOff = 256; }
    else if (r < 224) { src = Wo  + layer*65536;  dst = Wo_t   + layer*65536;  N = 256;  int t2 = r - 160; tk = t2 >> 3; tn = t2 & 7;  dstLd = 256;  }
    else if (r < 480) { src = W1  + layer*262144; dst = W1_t   + layer*262144; N = 1024; int t2 = r - 224; tk = t2 >> 5; tn = t2 & 31; dstLd = 256;  }
    else              { src = W2  + layer*262144; dst = W2_t   + layer*262144; N = 256;  int t2 = r - 480; tk = t2 >> 3; tn = t2 & 7;  dstLd = 1024; }
    int k0 = tk * 32, n0 = tn * 32;
    int tx = threadIdx.x & 31, ty = threadIdx.x >> 5;
    #pragma unroll
    for (int i = 0; i < 4; ++i)
        tile[ty + i*8][tx] = src[(size_t)(k0 + ty + i*8) * N + n0 + tx];
    __syncthreads();
    #pragma unroll
    for (int i = 0; i < 4; ++i)
        dst[(size_t)(dstRowOff + n0 + ty + i*8) * dstLd + k0 + tx] =
            f2bf(tile[tx][ty + i*8]);
}

// ---------------------------------------------------------------------------
// bf16 MFMA GEMM: C(M,N) = A(M,K)bf16 @ Bt(N,K)bf16^T + bias.
// BM=128, BN=64, BK=32; 256 threads = 4 waves (2x2); per wave 64x32 out.
// A staged via global_load_lds (linear dest, pre-swizzled source); LDS reads
// XOR-swizzled (kb ^= row&3) to spread banks. fp32 accum in 16x16x32 MFMA.
// ---------------------------------------------------------------------------
template<bool RELU, bool OUTBF>
__global__ __launch_bounds__(256) void mfma_gemm(
    const unsigned short* __restrict__ A, const unsigned short* __restrict__ Bt,
    const float* __restrict__ bias, const float* __restrict__ bias2, int split,
    void* __restrict__ Cout, int M, int N, int K)
{
    __shared__ __align__(16) unsigned short lds[6144]; // A [128][32] @0B, B [64][32] @8192B
    const int tid  = threadIdx.x;
    const int lane = tid & 63, wave = tid >> 6;
    const int wm = wave >> 1, wn = wave & 1;
    const int row0 = blockIdx.y * 128, col0 = blockIdx.x * 64;
    const int l15 = lane & 15, l4 = lane >> 4;
    char* ldsb = (char*)lds;

    // staging: A = 2 wave-instructions x 64 lanes x 16B, B = 1
    const unsigned short* aSrc[2]; char* aDst[2];
    #pragma unroll
    for (int i = 0; i < 2; ++i) {
        int u = i*256 + wave*64 + lane;
        int rr = u >> 2, kb = u & 3, kbd = kb ^ (rr & 3);
        aSrc[i] = A + (size_t)(row0 + rr) * K + kbd * 8;
        aDst[i] = ldsb + (i*256 + wave*64) * 16;
    }
    const unsigned short* bSrc; char* bDst;
    {
        int u = tid, cc = u >> 2, kb = u & 3, kbd = kb ^ (cc & 3);
        bSrc = Bt + (size_t)(col0 + cc) * K + kbd * 8;
        bDst = ldsb + 8192 + wave * 1024;
    }

    // swizzled read offsets (constant across K iterations)
    int a_off[4], b_off[2];
    #pragma unroll
    for (int mf = 0; mf < 4; ++mf) {
        int rr = wm*64 + mf*16 + l15;
        a_off[mf] = rr*64 + ((l4 ^ (rr & 3)) << 4);
    }
    #pragma unroll
    for (int nf = 0; nf < 2; ++nf) {
        int cc = wn*32 + nf*16 + l15;
        b_off[nf] = 8192 + cc*64 + ((l4 ^ (cc & 3)) << 4);
    }

    f32x4 acc[4][2];
    #pragma unroll
    for (int mf = 0; mf < 4; ++mf)
        #pragma unroll
        for (int nf = 0; nf < 2; ++nf)
            acc[mf][nf] = (f32x4)(0.f);

    for (int k0 = 0; k0 < K; k0 += 32) {
        GLDS(aSrc[0] + k0, aDst[0]);
        GLDS(aSrc[1] + k0, aDst[1]);
        GLDS(bSrc    + k0, bDst);
        __syncthreads();          // drains vmcnt + syncs waves
        bf16x8 bfr[2];
        #pragma unroll
        for (int nf = 0; nf < 2; ++nf)
            bfr[nf] = *(const bf16x8*)(ldsb + b_off[nf]);
        #pragma unroll
        for (int mf = 0; mf < 4; ++mf) {
            bf16x8 afr = *(const bf16x8*)(ldsb + a_off[mf]);
            #pragma unroll
            for (int nf = 0; nf < 2; ++nf)
                acc[mf][nf] = __builtin_amdgcn_mfma_f32_16x16x32_bf16(
                    afr, bfr[nf], acc[mf][nf], 0, 0, 0);
        }
        __syncthreads();
    }

    #pragma unroll
    for (int nf = 0; nf < 2; ++nf) {
        int col = col0 + wn*32 + nf*16 + l15;
        float bb = (col < split) ? bias[col] : bias2[col - split];
        #pragma unroll
        for (int mf = 0; mf < 4; ++mf) {
            #pragma unroll
            for (int i = 0; i < 4; ++i) {
                int row = row0 + wm*64 + mf*16 + l4*4 + i;
                if (row < M) {
                    float v = acc[mf][nf][i] + bb;
                    if (RELU) v = fmaxf(v, 0.f);
                    if (OUTBF)
                        ((unsigned short*)Cout)[(size_t)row * N + col] = f2bf(v);
                    else
                        ((float*)Cout)[(size_t)row * N + col] = v;
                }
            }
        }
    }
}

// ---------------------------------------------------------------------------
// MSDA sampling: softmax over 16 logits + bilinear sample + weighted sum.
// One thread per (b, t, head, quarter-of-HD). Output bf16 (GEMM A operand).
// ---------------------------------------------------------------------------
__global__ __launch_bounds__(256) void msda_kernel(
    const float* __restrict__ value,     // (b*t, NH*HD) fp32
    const float* __restrict__ offattn,   // (b*t, 384): [0,256)=off, [256,384)=attn
    unsigned short* __restrict__ outb)   // (b*t, NH*HD) bf16
{
    int gid = blockIdx.x * 256 + threadIdx.x;
    if (gid >= MROWS * NHEAD * 8) return;
    int part = gid & 7;
    int h    = (gid >> 3) & 7;
    int bt   = gid >> 6;
    int b    = (bt >= LEN) ? 1 : 0;
    int t    = bt - b * LEN;

    const float* lg = offattn + (size_t)bt * 384 + 256 + h * 16;
    float w[16];
    float mx = -1e30f;
    #pragma unroll
    for (int j = 0; j < 16; ++j) { w[j] = lg[j]; mx = fmaxf(mx, w[j]); }
    float s = 0.f;
    #pragma unroll
    for (int j = 0; j < 16; ++j) { w[j] = __expf(w[j] - mx); s += w[j]; }
    float inv = 1.f / s;

    int li, Wr;
    if (t < 2304)      { li = t;        Wr = 48; }
    else if (t < 2880) { li = t - 2304; Wr = 24; }
    else if (t < 3024) { li = t - 2880; Wr = 12; }
    else               { li = t - 3024; Wr = 6;  }
    float refx = ((li % Wr) + 0.5f) / (float)Wr;
    float refy = ((li / Wr) + 0.5f) / (float)Wr;

    const float* offp    = offattn + (size_t)bt * 384 + h * 32;
    const float* valbase = value + (size_t)b * LEN * D_MODEL + h * HDIM + part * 4;

    const int starts[4] = {0, 2304, 2880, 3024};
    const int Ws[4]     = {48, 24, 12, 6};

    float4 acc = make_float4(0.f, 0.f, 0.f, 0.f);

    #pragma unroll
    for (int lv = 0; lv < NLVL; ++lv) {
        int Wl = Ws[lv];
        int st = starts[lv];
        float fW = (float)Wl;
        #pragma unroll
        for (int p = 0; p < NPTS; ++p) {
            float ox = offp[(lv * NPTS + p) * 2 + 0];
            float oy = offp[(lv * NPTS + p) * 2 + 1];
            float x = (refx + ox / fW) * fW - 0.5f;
            float y = (refy + oy / fW) * fW - 0.5f;
            float x0f = floorf(x), y0f = floorf(y);
            float lx = x - x0f, ly = y - y0f;
            int x0 = (int)x0f, y0 = (int)y0f;
            float aw = w[lv * NPTS + p] * inv;
            float tw[4] = {(1.f - lx) * (1.f - ly), lx * (1.f - ly),
                           (1.f - lx) * ly,         lx * ly};
            const int dxs[4] = {0, 1, 0, 1};
            const int dys[4] = {0, 0, 1, 1};
            #pragma unroll
            for (int tap = 0; tap < 4; ++tap) {
                int xi = x0 + dxs[tap], yi = y0 + dys[tap];
                bool valid = (xi >= 0) & (xi < Wl) & (yi >= 0) & (yi < Wl);
                int xc = xi < 0 ? 0 : (xi > Wl - 1 ? Wl - 1 : xi);
                int yc = yi < 0 ? 0 : (yi > Wl - 1 ? Wl - 1 : yi);
                int tt = st + yc * Wl + xc;
                const float4 v = *(const float4*)(valbase + (size_t)tt * D_MODEL);
                float wt = valid ? aw * tw[tap] : 0.f;
                acc.x += wt * v.x; acc.y += wt * v.y;
                acc.z += wt * v.z; acc.w += wt * v.w;
            }
        }
    }
    ushort4 o = make_ushort4(f2bf(acc.x), f2bf(acc.y), f2bf(acc.z), f2bf(acc.w));
    *(ushort4*)(outb + (size_t)bt * D_MODEL + h * HDIM + part * 4) = o;
}

// ---------------------------------------------------------------------------
// Fused residual add + LayerNorm -> out fp32 (in place) + out bf16.
// ---------------------------------------------------------------------------
__global__ __launch_bounds__(256) void add_ln_kernel(
    float* __restrict__ out, unsigned short* __restrict__ outbf,
    const float* __restrict__ add,
    const float* __restrict__ g, const float* __restrict__ be)
{
    int row  = blockIdx.x * 4 + (threadIdx.x >> 6);
    int lane = threadIdx.x & 63;
    if (row >= MROWS) return;

    float4 x = ((const float4*)(out + (size_t)row * D_MODEL))[lane];
    float4 y = ((const float4*)(add + (size_t)row * D_MODEL))[lane];
    x.x += y.x; x.y += y.y; x.z += y.z; x.w += y.w;

    float s  = x.x + x.y + x.z + x.w;
    float ss = x.x * x.x + x.y * x.y + x.z * x.z + x.w * x.w;
    #pragma unroll
    for (int m = 1; m < 64; m <<= 1) {
        s  += __shfl_xor(s, m);
        ss += __shfl_xor(ss, m);
    }
    float mean = s * (1.f / 256.f);
    float var  = ss * (1.f / 256.f) - mean * mean;
    float rstd = rsqrtf(var + 1e-5f);

    float4 gv = ((const float4*)g)[lane];
    float4 bv = ((const float4*)be)[lane];
    float4 o;
    o.x = (x.x - mean) * rstd * gv.x + bv.x;
    o.y = (x.y - mean) * rstd * gv.y + bv.y;
    o.z = (x.z - mean) * rstd * gv.z + bv.z;
    o.w = (x.w - mean) * rstd * gv.w + bv.w;
    ((float4*)(out + (size_t)row * D_MODEL))[lane] = o;
    ((ushort4*)(outbf + (size_t)row * D_MODEL))[lane] =
        make_ushort4(f2bf(o.x), f2bf(o.y), f2bf(o.z), f2bf(o.w));
}

// ---------------------------------------------------------------------------
__global__ void tail_kernel(float* __restrict__ tail)
{
    if (threadIdx.x == 0 && blockIdx.x == 0) {
        const float vals[12] = {48.f, 48.f, 24.f, 24.f, 12.f, 12.f, 6.f, 6.f,
                                0.f, 2304.f, 2880.f, 3024.f};
        #pragma unroll
        for (int i = 0; i < 12; ++i) tail[i] = vals[i];
    }
}

// ---------------------------------------------------------------------------
extern "C" void kernel_launch(void* const* d_in, const int* in_sizes, int n_in,
                              void* d_out, int out_size, void* d_ws, size_t ws_size,
                              hipStream_t stream)
{
    const float* SRC[4]; const float* POS[4];
    bool interleaved = (in_sizes[1] == in_sizes[0]);
    if (interleaved) {
        SRC[0] = (const float*)d_in[0]; POS[0] = (const float*)d_in[1];
        SRC[1] = (const float*)d_in[2]; POS[1] = (const float*)d_in[3];
        SRC[2] = (const float*)d_in[4]; POS[2] = (const float*)d_in[5];
        SRC[3] = (const float*)d_in[6]; POS[3] = (const float*)d_in[7];
    } else {
        for (int i = 0; i < 4; ++i) {
            SRC[i] = (const float*)d_in[i];
            POS[i] = (const float*)d_in[4 + i];
        }
    }
    const float* lemb  = (const float*)d_in[8];
    const float* Wv    = (const float*)d_in[9];
    const float* bv    = (const float*)d_in[10];
    const float* Woff  = (const float*)d_in[11];
    const float* boff  = (const float*)d_in[12];
    const float* Wa    = (const float*)d_in[13];
    const float* ba    = (const float*)d_in[14];
    const float* Wo    = (const float*)d_in[15];
    const float* bo    = (const float*)d_in[16];
    const float* g1    = (const float*)d_in[17];
    const float* beta1 = (const float*)d_in[18];
    const float* W1    = (const float*)d_in[19];
    const float* bf1   = (const float*)d_in[20];
    const float* W2    = (const float*)d_in[21];
    const float* bf2   = (const float*)d_in[22];
    const float* g2    = (const float*)d_in[23];
    const float* beta2 = (const float*)d_in[24];

    float* out = (float*)d_out;                   // (b*t, D) residual, fp32

    // ---- workspace layout ----
    char* ws = (char*)d_ws;
    float* pos     = (float*)ws;                                   ws += (size_t)MPAD * 256 * 4;
    float* val     = (float*)ws;                                   ws += (size_t)MPAD * 256 * 4;
    float* offattn = (float*)ws;                                   ws += (size_t)MPAD * 384 * 4;
    float* tmp     = (float*)ws;                                   ws += (size_t)MPAD * 256 * 4;
    unsigned short* qbf    = (unsigned short*)ws;                  ws += (size_t)MPAD * 256 * 2;
    unsigned short* outbf  = (unsigned short*)ws;                  ws += (size_t)MPAD * 256 * 2;
    unsigned short* msdabf = (unsigned short*)ws;                  ws += (size_t)MPAD * 256 * 2;
    unsigned short* hbuf   = (unsigned short*)ws;                  ws += (size_t)MPAD * 1024 * 2;
    unsigned short* Wv_t    = (unsigned short*)ws;                 ws += (size_t)6 * 65536 * 2;
    unsigned short* Woffa_t = (unsigned short*)ws;                 ws += (size_t)6 * 98304 * 2;
    unsigned short* Wo_t    = (unsigned short*)ws;                 ws += (size_t)6 * 65536 * 2;
    unsigned short* W1_t    = (unsigned short*)ws;                 ws += (size_t)6 * 262144 * 2;
    unsigned short* W2_t    = (unsigned short*)ws;                 ws += (size_t)6 * 262144 * 2;

    // ---- weight transpose/convert (all layers, one launch) ----
    wconv_kernel<<<6 * 736, 256, 0, stream>>>(Wv, Woff, Wa, Wo, W1, W2,
                                              Wv_t, Woffa_t, Wo_t, W1_t, W2_t);

    const int nElem = MROWS * D_MODEL;
    flatten_kernel<<<(nElem + 255) / 256, 256, 0, stream>>>(
        SRC[0], SRC[1], SRC[2], SRC[3], POS[0], POS[1], POS[2], POS[3],
        lemb, out, outbf, pos);

    const int n4 = nElem / 4;
    const dim3 g256(256 / 64, MPAD / 128);    // (4, 48)
    const dim3 g384(384 / 64, MPAD / 128);    // (6, 48)
    const dim3 g1024(1024 / 64, MPAD / 128);  // (16, 48)

    for (int l = 0; l < NLAYERS; ++l) {
        const unsigned short* Wv_l   = Wv_t    + (size_t)l * 65536;
        const unsigned short* Woffa_l= Woffa_t + (size_t)l * 98304;
        const unsigned short* Wo_l   = Wo_t    + (size_t)l * 65536;
        const unsigned short* W1_l   = W1_t    + (size_t)l * 262144;
        const unsigned short* W2_l   = W2_t    + (size_t)l * 262144;
        const float* bv_l  = bv   + l * 256;
        const float* boff_l= boff + l * 256;
        const float* ba_l  = ba   + l * 128;
        const float* bo_l  = bo   + l * 256;
        const float* bf1_l = bf1  + l * DFF;
        const float* bf2_l = bf2  + l * 256;

        // q = out + pos (bf16)
        addq_kernel<<<(n4 + 255) / 256, 256, 0, stream>>>(
            (const float4*)out, (const float4*)pos, (ushort4*)qbf, n4);

        // value = out @ Wv + bv  (fp32 out, consumed by msda)
        mfma_gemm<false, false><<<g256, 256, 0, stream>>>(
            outbf, Wv_l, bv_l, bv_l, 256, val, MROWS, 256, 256);

        // [off | attn] = q @ [Woff | Wa] + [boff | ba]
        mfma_gemm<false, false><<<g384, 256, 0, stream>>>(
            qbf, Woffa_l, boff_l, ba_l, 256, offattn, MROWS, 384, 256);

        // deformable sampling -> bf16
        msda_kernel<<<(MROWS * NHEAD * 8 + 255) / 256, 256, 0, stream>>>(
            val, offattn, msdabf);

        // out-proj: tmp = msda @ Wo + bo
        mfma_gemm<false, false><<<g256, 256, 0, stream>>>(
            msdabf, Wo_l, bo_l, bo_l, 256, tmp, MROWS, 256, 256);

        // out = LN(out + tmp)
        add_ln_kernel<<<MROWS / 4, 256, 0, stream>>>(
            out, outbf, tmp, g1 + l * 256, beta1 + l * 256);

        // h = relu(out @ W1 + bf1) -> bf16
        mfma_gemm<true, true><<<g1024, 256, 0, stream>>>(
            outbf, W1_l, bf1_l, bf1_l, 1024, hbuf, MROWS, 1024, 256);

        // tmp = h @ W2 + bf2
        mfma_gemm<false, false><<<g256, 256, 0, stream>>>(
            hbuf, W2_l, bf2_l, bf2_l, 256, tmp, MROWS, 256, 1024);

        // out = LN(out + tmp)
        add_ln_kernel<<<MROWS / 4, 256, 0, stream>>>(
            out, outbf, tmp, g2 + l * 256, beta2 + l * 256);
    }

    tail_kernel<<<1, 64, 0, stream>>>(out + (size_t)MROWS * D_MODEL);
}